// Round 8
// baseline (247.791 us; speedup 1.0000x reference)
//
#include <hip/hip_runtime.h>

// B=16, Q=2048, K=2048, D=128, DV=128
// out[b,q,:] = softmax_k((q.k - 0.5||k||^2)/sqrt(192), mask k>=valid_len) @ V
// R16: deterministic split-pair balance. R14/R15 showed makespan is set by the
// longest job (32 serial tiles ~ 57us) and that dispatch-order guesses fail
// (R15: batch scatter -> FETCH x4). Fix with NO dispatch assumptions:
// per batch, sorted job q has T_q ~ q+1 tiles; block (b,i) processes
// {lower half of job i} then {upper half of job 31-i} -> every block has
// ceil(T_i/2)+floor(T_{31-i}/2) ~ 16.5 tiles, uniform by construction, same
// batch both phases (keeps R14's L2-friendly static mapping). Job halves
// merge via R10's proven arrival-order protocol (raw partial in Og + psums in
// ws; first-arriver flags, second merges+normalizes; spin is bounded because
// the partner has provably passed its flagA increment).

#define Bn   16
#define Qn   2048
#define Kn   2048
#define Dn   128
#define DVn  128
#define BQ   64
#define BK   64

// (1/sqrt(192)) * log2(e) : softmax computed as 2^(qk*SC2 + bias2)
#define SC2 0.10411754f

typedef short bf16x4 __attribute__((ext_vector_type(4)));
typedef short bf16x8 __attribute__((ext_vector_type(8)));
typedef float f32x16 __attribute__((ext_vector_type(16)));

__device__ __forceinline__ short f2bf(float x) {   // RNE
    union { float f; unsigned u; } v; v.f = x;
    unsigned r = (v.u + 0x7fffu + ((v.u >> 16) & 1u)) >> 16;
    return (short)r;
}

typedef const __attribute__((address_space(1))) void* gas_t;
typedef __attribute__((address_space(3))) void* las_t;
__device__ __forceinline__ void gld16(const void* g, void* l) {
    __builtin_amdgcn_global_load_lds((gas_t)g, (las_t)l, 16, 0, 0);
}
__device__ __forceinline__ void gld4(const void* g, void* l) {
    __builtin_amdgcn_global_load_lds((gas_t)g, (las_t)l, 4, 0, 0);
}
__device__ __forceinline__ float exp2_raw(float a) {  // D = 2^S0
    float p;
    asm("v_exp_f32 %0, %1" : "=v"(p) : "v"(a));
    return p;
}

// ---------- preprocess: K/V convert + q-sort + flag zeroing ----------
__global__ __launch_bounds__(256) void prep_kv(const float* __restrict__ Kg,
                                               const float* __restrict__ Vg,
                                               const int* __restrict__ VLg,
                                               short* __restrict__ Kb,
                                               short* __restrict__ Vtb,
                                               float* __restrict__ biasg,
                                               int* __restrict__ perm,
                                               int* __restrict__ flags) {
    const int tid = threadIdx.x;
    if (blockIdx.x < 1024) {
        // ---- K path: 32 rows (b*Kn+row flat) per block, fully coalesced ----
        const int rowbase = blockIdx.x * 32;
        const float* src = Kg + (size_t)rowbase * Dn;
        short*       dst = Kb + (size_t)rowbase * Dn;
#pragma unroll
        for (int p = 0; p < 4; ++p) {
            const int idx = p * 1024 + tid * 4;     // flat float index
            float4 x = *(const float4*)(src + idx);
            bf16x4 h;
            h[0] = f2bf(x.x); h[1] = f2bf(x.y); h[2] = f2bf(x.z); h[3] = f2bf(x.w);
            *(bf16x4*)(dst + idx) = h;
            float ssq = x.x*x.x + x.y*x.y + x.z*x.z + x.w*x.w;
            ssq += __shfl_xor(ssq, 1);
            ssq += __shfl_xor(ssq, 2);
            ssq += __shfl_xor(ssq, 4);
            ssq += __shfl_xor(ssq, 8);
            ssq += __shfl_xor(ssq, 16);
            if ((tid & 31) == 0)
                biasg[rowbase + p * 8 + (tid >> 5)] = -0.5f * ssq * SC2;
        }
    } else if (blockIdx.x < 1536) {
        // ---- V path: transpose one [64 k][128 v] tile to plain V^T bf16 ----
        const int blk = blockIdx.x - 1024;
        const int b  = blk >> 5;
        const int k0 = (blk & 31) * 64;
        __shared__ short Ls[64 * 128];
#pragma unroll
        for (int p = 0; p < 8; ++p) {
            const int kk = p * 8 + (tid >> 5);      // tile row 0..63
            const int v0 = (tid & 31) * 4;
            float4 x = *(const float4*)(Vg + ((size_t)b * Kn + k0 + kk) * DVn + v0);
            bf16x4 h;
            h[0] = f2bf(x.x); h[1] = f2bf(x.y); h[2] = f2bf(x.z); h[3] = f2bf(x.w);
            const int vs = v0 ^ ((kk & 15) << 3);   // keeps 4-short alignment
            *(bf16x4*)&Ls[kk * 128 + vs] = h;
        }
        __syncthreads();
        const int v = tid >> 1;
        const int h = (tid & 1) * 32;
        short* dst = Vtb + ((size_t)b * DVn + v) * Kn + k0 + h;
#pragma unroll
        for (int j4 = 0; j4 < 4; ++j4) {
            bf16x8 o;
#pragma unroll
            for (int j = 0; j < 8; ++j) {
                const int kk = h + j4 * 8 + j;
                o[j] = Ls[kk * 128 + (v ^ ((kk & 15) << 3))];
            }
            *(bf16x8*)(dst + j4 * 8) = o;
        }
    } else {
        // ---- sort path: counting sort of 2048 q-rows by valid_len, batch b ----
        const int b = blockIdx.x - 1536;
        __shared__ int hist[2048];
        __shared__ int part[256];
        int vq[8];
        if (tid < 32) {                  // zero this batch's merge flags
            flags[b * 32 + tid] = 0;           // flagA
            flags[512 + b * 32 + tid] = 0;     // flagB
        }
#pragma unroll
        for (int i = 0; i < 8; ++i) hist[i * 256 + tid] = 0;
        __syncthreads();
#pragma unroll
        for (int i = 0; i < 8; ++i) {
            vq[i] = VLg[b * Qn + i * 256 + tid];    // 1..2048
            atomicAdd(&hist[vq[i] - 1], 1);
        }
        __syncthreads();
        // exclusive scan over 2048 bins (8 per thread + block scan)
        int lex[8]; int s = 0;
#pragma unroll
        for (int j = 0; j < 8; ++j) { lex[j] = s; s += hist[tid * 8 + j]; }
        part[tid] = s;
        __syncthreads();
        for (int off = 1; off < 256; off <<= 1) {
            int v = (tid >= off) ? part[tid - off] : 0;
            __syncthreads();
            part[tid] += v;
            __syncthreads();
        }
        const int excl = part[tid] - s;
#pragma unroll
        for (int j = 0; j < 8; ++j) hist[tid * 8 + j] = excl + lex[j];
        __syncthreads();
#pragma unroll
        for (int i = 0; i < 8; ++i) {
            const int pos = atomicAdd(&hist[vq[i] - 1], 1);
            perm[b * Qn + pos] = i * 256 + tid;
        }
    }
}

// epilogue helpers with LITERAL accumulator indices (no runtime Oacc[] index)
#define DUMP_ACC(ACC, DST)                                            \
    {                                                                 \
        _Pragma("unroll")                                             \
        for (int reg = 0; reg < 16; ++reg) {                          \
            const int row = (reg & 3) + 8 * (reg >> 2) + 4 * hi;      \
            (DST)[row * 32 + l31] = (ACC)[reg];                       \
        }                                                             \
    }
#define STORE_RAW(ACC, SRC, COLBASE)                                  \
    {                                                                 \
        _Pragma("unroll")                                             \
        for (int reg = 0; reg < 16; ++reg) {                          \
            const int row = (reg & 3) + 8 * (reg >> 2) + 4 * hi;      \
            Og_b[(size_t)permSh[pair * 32 + row] * DVn + (COLBASE) + l31] \
                = (ACC)[reg] + (SRC)[row * 32 + l31];                 \
        }                                                             \
    }
#define STORE_MRG(ACC, SRC, COLBASE)                                  \
    {                                                                 \
        _Pragma("unroll")                                             \
        for (int reg = 0; reg < 16; ++reg) {                          \
            const int row = (reg & 3) + 8 * (reg >> 2) + 4 * hi;      \
            const size_t off = (size_t)permSh[pair * 32 + row] * DVn  \
                               + (COLBASE) + l31;                     \
            const float o = (ACC)[reg] + (SRC)[row * 32 + l31] + Og_b[off]; \
            Og_b[off] = o * invl[reg];                                \
        }                                                             \
    }

// ---------- main attention kernel: 2 phases/block, split-job merge ----------
__global__ __launch_bounds__(256, 2) void attn_kernel(
    const float* __restrict__ Qg, const short* __restrict__ Kb,
    const short* __restrict__ Vtb, const float* __restrict__ biasg,
    const int* __restrict__ VL, const int* __restrict__ perm,
    float* __restrict__ psums, int* __restrict__ flags,
    float* __restrict__ Og)
{
    __shared__ __align__(16) short Ksh[2][64 * 128];   // 32768 B (epilogue: float slab)
    __shared__ __align__(16) short Vsh[2][64 * 128];   // 32768 B
    __shared__ __align__(16) float biasSh[2][64];      //   512 B
    __shared__ float Lsum[4][32];                      //   512 B
    __shared__ int   permSh[64];                       //   256 B
    __shared__ int   roleSh;

    const int tid  = threadIdx.x;
    const int lane = tid & 63;
    const int w    = tid >> 6;    // wave 0..3
    const int pair = w >> 1;      // q-strip: rows [pair*32, pair*32+32)
    const int half = w & 1;       // key-half (S and PV k-range), wave-uniform
    const int l31  = lane & 31;
    const int hi   = lane >> 5;

    const int lin  = blockIdx.x;          // 0..511 ; R8/R14 XCD-friendly mapping
    const int slot = lin >> 3;
    const int b    = (lin & 7) * 2 + (slot >> 5);
    const int i    = slot & 31;

    const short* Kb_b = Kb  + (size_t)b * Kn * Dn;
    const short* Vt_b = Vtb + (size_t)b * DVn * Kn;
    const float* bias_b = biasg + b * Kn;
    float* Og_b = Og + (size_t)b * Qn * DVn;
    int* flagA = flags;
    int* flagB = flags + 512;

    // ---- DMA source pointers (job-independent; depend only on b) ----
    const short* ksp[4]; int kdo[4];
    const short* vsp[4]; int vdo[4];
#pragma unroll
    for (int u = 0; u < 4; ++u) {
        const int rl = w * 16 + u * 4 + (lane >> 4);       // K tile row 0..63
        const int ch = (lane & 15) ^ (rl & 15);
        ksp[u] = Kb_b + (size_t)rl * Dn + ch * 8;
        kdo[u] = (w * 16 + u * 4) * 128;
        const int rv = rl;
        const int cc = (lane & 15) ^ (rv & 15);            // source chunk
        const int vv = 2 * rv + (cc >> 3);
        vsp[u] = Vt_b + (size_t)vv * Kn + (cc & 7) * 8;
        vdo[u] = (w * 16 + u * 4) * 128;
    }
    const int kr = half * 32 + l31;

#pragma unroll 1
    for (int ph = 0; ph < 2; ++ph) {
        const int jq = ph ? (31 - i) : i;
        __syncthreads();                         // prior phase LDS fully done
        if (tid < 64) permSh[tid] = perm[b * Qn + jq * BQ + tid];
        __syncthreads();

        // ---- Q fragments (gathered via perm) ----
        const int qperm = permSh[pair * 32 + l31];
        bf16x8 qf[8];
        {
            const float* qrow = Qg + ((size_t)b * Qn + qperm) * Dn;
#pragma unroll
            for (int kt = 0; kt < 8; ++kt) {
                const float* p = qrow + kt * 16 + hi * 8;
                float4 x0 = *(const float4*)(p);
                float4 x1 = *(const float4*)(p + 4);
                bf16x8 f;
                f[0]=f2bf(x0.x); f[1]=f2bf(x0.y); f[2]=f2bf(x0.z); f[3]=f2bf(x0.w);
                f[4]=f2bf(x1.x); f[5]=f2bf(x1.y); f[6]=f2bf(x1.z); f[7]=f2bf(x1.w);
                qf[kt] = f;
            }
        }
        const int vlq = VL[b * Qn + qperm];
        const int T   = (VL[b * Qn + permSh[63]] + BK - 1) >> 6;  // tiles of this job
        const int TL  = (T + 1) >> 1;
        const int tA  = ph ? TL : 0;             // tile range of this phase
        const int tB  = ph ? T  : TL;
        const int kbeg = tA * BK, kend = tB * BK;

        f32x16 Oacc[4];
#pragma unroll
        for (int nt = 0; nt < 4; ++nt)
#pragma unroll
            for (int j = 0; j < 16; ++j) Oacc[nt][j] = 0.f;
        float psum = 0.f;

        if (tA < tB) {
            // prologue: DMA tile tA into buffer tA&1
            const int b0 = tA & 1;
#pragma unroll
            for (int u = 0; u < 4; ++u) {
                gld16(ksp[u] + (size_t)kbeg * Dn, &Ksh[b0][kdo[u]]);
                gld16(vsp[u] + kbeg,              &Vsh[b0][vdo[u]]);
            }
            if (w == 0) gld4(bias_b + kbeg + lane, &biasSh[b0][0]);

            for (int k0k = kbeg; k0k < kend; k0k += BK) {
                const int buf = (k0k >> 6) & 1;
                __syncthreads();   // drains vmcnt(0): tile ready; prev readers done

                if (k0k + BK < kend) {
                    const int nk = k0k + BK;
#pragma unroll
                    for (int u = 0; u < 4; ++u) {
                        gld16(ksp[u] + (size_t)nk * Dn, &Ksh[buf ^ 1][kdo[u]]);
                        gld16(vsp[u] + nk,              &Vsh[buf ^ 1][vdo[u]]);
                    }
                    if (w == 0) gld4(bias_b + nk + lane, &biasSh[buf ^ 1][0]);
                }

                float4 bv[4];
#pragma unroll
                for (int rq = 0; rq < 4; ++rq)
                    bv[rq] = *(const float4*)&biasSh[buf][half * 32 + rq * 8 + hi * 4];

                // ---- S^T = K_half . Q^T : one 32x32 tile per wave (8 MFMA) ----
                const short* kbuf = Ksh[buf];
                f32x16 Sv;
#pragma unroll
                for (int j = 0; j < 16; ++j) Sv[j] = 0.f;
#pragma unroll
                for (int kt = 0; kt < 8; ++kt) {
                    bf16x8 kf = *(const bf16x8*)&kbuf[kr * 128 + (((kt*2 + hi) ^ (kr & 15)) * 8)];
                    Sv = __builtin_amdgcn_mfma_f32_32x32x16_bf16(kf, qf[kt], Sv, 0, 0, 0);
                }

                // ---- softmax in exp2 domain ----
#pragma unroll
                for (int rq = 0; rq < 4; ++rq) {
#pragma unroll
                    for (int r = 0; r < 4; ++r) {
                        const int reg = rq * 4 + r;
                        const int keyg = k0k + half * 32 + rq * 8 + hi * 4 + r;
                        float a = fmaf(Sv[reg], SC2, bv[rq][r]);
                        a = (keyg < vlq) ? a : -200.0f;
                        const float p = exp2_raw(a);
                        psum += p;
                        Sv[reg] = p;
                    }
                }

                // ---- PV: C-layout -> A-layout via lane^32 exchange; 8 MFMA ----
                const short* vbuf = Vsh[buf];
#pragma unroll
                for (int kt = 0; kt < 2; ++kt) {
                    unsigned kAx = __builtin_amdgcn_perm(__float_as_uint(Sv[(2*kt)*4+1]),
                                                         __float_as_uint(Sv[(2*kt)*4+0]), 0x07060302u);
                    unsigned kAy = __builtin_amdgcn_perm(__float_as_uint(Sv[(2*kt)*4+3]),
                                                         __float_as_uint(Sv[(2*kt)*4+2]), 0x07060302u);
                    unsigned kBx = __builtin_amdgcn_perm(__float_as_uint(Sv[(2*kt+1)*4+1]),
                                                         __float_as_uint(Sv[(2*kt+1)*4+0]), 0x07060302u);
                    unsigned kBy = __builtin_amdgcn_perm(__float_as_uint(Sv[(2*kt+1)*4+3]),
                                                         __float_as_uint(Sv[(2*kt+1)*4+2]), 0x07060302u);
                    const unsigned sx = hi ? kAx : kBx;
                    const unsigned sy = hi ? kAy : kBy;
                    const unsigned rx = __shfl_xor(sx, 32);
                    const unsigned ry = __shfl_xor(sy, 32);
                    uint4 au;
                    au.x = hi ? rx : kAx;
                    au.y = hi ? ry : kAy;
                    au.z = hi ? kBx : rx;
                    au.w = hi ? kBy : ry;
                    const bf16x8 af = __builtin_bit_cast(bf16x8, au);
                    const int kc = half * 4 + kt * 2 + hi;
#pragma unroll
                    for (int nt = 0; nt < 4; ++nt) {
                        const int v  = nt * 32 + l31;
                        const int r  = v >> 1;
                        const int p  = ((v & 1) * 8 + kc) ^ (r & 15);
                        bf16x8 vf = *(const bf16x8*)&vbuf[r * 128 + p * 8];
                        Oacc[nt] = __builtin_amdgcn_mfma_f32_32x32x16_bf16(af, vf, Oacc[nt], 0, 0, 0);
                    }
                }
            }
        }

        // ---- epilogue: combine key-halves across wave pairs via LDS ----
        psum += __shfl_xor(psum, 32);
        if (lane < 32) Lsum[w][l31] = psum;
        __syncthreads();   // all waves done reading Ksh/Vsh -> safe to reuse Ksh

        float* slab = (float*)&Ksh[0][0];
        {
            float* dst0 = slab + ((pair * 2 + (1 - half)) * 2 + 0) * 1024;
            float* dst1 = slab + ((pair * 2 + (1 - half)) * 2 + 1) * 1024;
            if (half == 0) {
                DUMP_ACC(Oacc[2], dst0);
                DUMP_ACC(Oacc[3], dst1);
            } else {
                DUMP_ACC(Oacc[0], dst0);
                DUMP_ACC(Oacc[1], dst1);
            }
        }
        __syncthreads();

        // per-thread partial denominators for this phase's k-range
        float psB[16];
#pragma unroll
        for (int rq = 0; rq < 4; ++rq)
#pragma unroll
            for (int r = 0; r < 4; ++r) {
                const int ql = r + 8 * rq + 4 * hi;
                psB[rq * 4 + r] = Lsum[pair * 2][ql] + Lsum[pair * 2 + 1][ql];
            }

        const int fid = b * 32 + jq;
        const float* src0 = slab + ((pair * 2 + half) * 2 + 0) * 1024;
        const float* src1 = slab + ((pair * 2 + half) * 2 + 1) * 1024;

        if (tid == 0) roleSh = atomicAdd(&flagA[fid], 1);
        __syncthreads();
        if (roleSh == 0) {
            // first-arriver: stage raw partial O in Og + psums in ws
            if (half == 0) {
                STORE_RAW(Oacc[0], src0, 0);
                STORE_RAW(Oacc[1], src1, 32);
            } else {
                STORE_RAW(Oacc[2], src0, 64);
                STORE_RAW(Oacc[3], src1, 96);
            }
            if (l31 == 0 && half == 0) {
#pragma unroll
                for (int reg = 0; reg < 16; ++reg) {
                    const int ql = (reg & 3) + 8 * (reg >> 2) + 4 * hi;
                    psums[fid * 64 + pair * 32 + ql] = psB[reg];
                }
            }
            __threadfence();
            __syncthreads();
            if (tid == 0) atomicExch(&flagB[fid], 1);
        } else {
            // second-arriver: partner already passed flagA -> spin is bounded
            if (tid == 0) {
                while (atomicAdd(&flagB[fid], 0) == 0) __builtin_amdgcn_s_sleep(2);
            }
            __syncthreads();
            __threadfence();
            float invl[16];
#pragma unroll
            for (int reg = 0; reg < 16; ++reg) {
                const int ql = (reg & 3) + 8 * (reg >> 2) + 4 * hi;
                invl[reg] = 1.f / (psB[reg] + psums[fid * 64 + pair * 32 + ql]);
            }
            if (half == 0) {
                STORE_MRG(Oacc[0], src0, 0);
                STORE_MRG(Oacc[1], src1, 32);
            } else {
                STORE_MRG(Oacc[2], src0, 64);
                STORE_MRG(Oacc[3], src1, 96);
            }
        }
    }
}

extern "C" void kernel_launch(void* const* d_in, const int* in_sizes, int n_in,
                              void* d_out, int out_size, void* d_ws, size_t ws_size,
                              hipStream_t stream) {
    const float* Qg = (const float*)d_in[0];
    const float* Kg = (const float*)d_in[1];
    const float* Vg = (const float*)d_in[2];
    const int*   VL = (const int*)d_in[3];
    float* Og = (float*)d_out;
    (void)ws_size;

    // ws: Kb bf16 (8MB) | Vtb bf16 (8MB) | bias f32 (128KB) | perm int (128KB)
    //     | psums f32 (128KB) | flags int (4KB)
    char* ws = (char*)d_ws;
    const size_t base = (size_t)Bn * Kn * Dn * 4;
    short* Kb    = (short*)(ws);
    short* Vtb   = (short*)(ws + (size_t)Bn * Kn * Dn * 2);
    float* bias  = (float*)(ws + base);
    int*   perm  = (int*)  (ws + base + 131072);
    float* psums = (float*)(ws + base + 262144);
    int*   flags = (int*)  (ws + base + 393216);

    prep_kv<<<dim3(1552), dim3(256), 0, stream>>>(Kg, Vg, VL, Kb, Vtb, bias,
                                                  perm, flags);
    attn_kernel<<<dim3(512), dim3(256), 0, stream>>>(Qg, Kb, Vtb, bias, VL,
                                                     perm, psums, flags, Og);
}

// Round 9
// 145.208 us; speedup vs baseline: 1.7065x; 1.7065x over previous
//
#include <hip/hip_runtime.h>

// B=16, Q=2048, K=2048, D=128, DV=128
// out[b,q,:] = softmax_k((q.k - 0.5||k||^2)/sqrt(192), mask k>=valid_len) @ V
// R17 = R14 (sorted varlen, R8 attn core, static XCD-batch map, NO inter-block
// coupling -- R16's merge protocol cost 3x) with a slot->job ordering that is
// balanced under BOTH plausible CU fill orders:
//   slots 0..31 (batch even):  [1,32,2,31,...,16,17]  (zip)
//   slots 32..63 (batch odd):  [32,1,31,2,...,17,16]  (complement)
// => f(s)+f(s^1)=33 (CU-major pairing) AND f(s)+f(s+32)=33 (slot-major
// pairing). R14's 57us matched CU-major fill pairing two ascending neighbors
// (makespan ~63 tiles); this ordering gives ~33 tiles/CU either way.
// Mapping: t=(slot&31)>>1, e=slot&1, bsel=slot>>5; q=(e^bsel)?31-t:t.

#define Bn   16
#define Qn   2048
#define Kn   2048
#define Dn   128
#define DVn  128
#define BQ   64
#define BK   64

// (1/sqrt(192)) * log2(e) : softmax computed as 2^(qk*SC2 + bias2)
#define SC2 0.10411754f

typedef short bf16x4 __attribute__((ext_vector_type(4)));
typedef short bf16x8 __attribute__((ext_vector_type(8)));
typedef float f32x16 __attribute__((ext_vector_type(16)));

__device__ __forceinline__ short f2bf(float x) {   // RNE
    union { float f; unsigned u; } v; v.f = x;
    unsigned r = (v.u + 0x7fffu + ((v.u >> 16) & 1u)) >> 16;
    return (short)r;
}

typedef const __attribute__((address_space(1))) void* gas_t;
typedef __attribute__((address_space(3))) void* las_t;
__device__ __forceinline__ void gld16(const void* g, void* l) {
    __builtin_amdgcn_global_load_lds((gas_t)g, (las_t)l, 16, 0, 0);
}
__device__ __forceinline__ void gld4(const void* g, void* l) {
    __builtin_amdgcn_global_load_lds((gas_t)g, (las_t)l, 4, 0, 0);
}
__device__ __forceinline__ float exp2_raw(float a) {  // D = 2^S0
    float p;
    asm("v_exp_f32 %0, %1" : "=v"(p) : "v"(a));
    return p;
}

// ---------- preprocess: K/V convert (coalesced) + per-batch q-sort ----------
__global__ __launch_bounds__(256) void prep_kv(const float* __restrict__ Kg,
                                               const float* __restrict__ Vg,
                                               const int* __restrict__ VLg,
                                               short* __restrict__ Kb,
                                               short* __restrict__ Vtb,
                                               float* __restrict__ biasg,
                                               int* __restrict__ perm) {
    const int tid = threadIdx.x;
    if (blockIdx.x < 1024) {
        // ---- K path: 32 rows (b*Kn+row flat) per block, fully coalesced ----
        const int rowbase = blockIdx.x * 32;
        const float* src = Kg + (size_t)rowbase * Dn;
        short*       dst = Kb + (size_t)rowbase * Dn;
#pragma unroll
        for (int p = 0; p < 4; ++p) {
            const int idx = p * 1024 + tid * 4;     // flat float index
            float4 x = *(const float4*)(src + idx);
            bf16x4 h;
            h[0] = f2bf(x.x); h[1] = f2bf(x.y); h[2] = f2bf(x.z); h[3] = f2bf(x.w);
            *(bf16x4*)(dst + idx) = h;
            float ssq = x.x*x.x + x.y*x.y + x.z*x.z + x.w*x.w;
            ssq += __shfl_xor(ssq, 1);
            ssq += __shfl_xor(ssq, 2);
            ssq += __shfl_xor(ssq, 4);
            ssq += __shfl_xor(ssq, 8);
            ssq += __shfl_xor(ssq, 16);
            if ((tid & 31) == 0)
                biasg[rowbase + p * 8 + (tid >> 5)] = -0.5f * ssq * SC2;
        }
    } else if (blockIdx.x < 1536) {
        // ---- V path: transpose one [64 k][128 v] tile to plain V^T bf16 ----
        const int blk = blockIdx.x - 1024;
        const int b  = blk >> 5;
        const int k0 = (blk & 31) * 64;
        __shared__ short Ls[64 * 128];
        // phase 1: coalesced float4 row reads; XOR-swizzled LDS writes
#pragma unroll
        for (int p = 0; p < 8; ++p) {
            const int kk = p * 8 + (tid >> 5);      // tile row 0..63
            const int v0 = (tid & 31) * 4;
            float4 x = *(const float4*)(Vg + ((size_t)b * Kn + k0 + kk) * DVn + v0);
            bf16x4 h;
            h[0] = f2bf(x.x); h[1] = f2bf(x.y); h[2] = f2bf(x.z); h[3] = f2bf(x.w);
            const int vs = v0 ^ ((kk & 15) << 3);   // keeps 4-short alignment
            *(bf16x4*)&Ls[kk * 128 + vs] = h;
        }
        __syncthreads();
        // phase 2: column gather (32 scalar reads) + coalesced 64B stores
        const int v = tid >> 1;
        const int h = (tid & 1) * 32;
        short* dst = Vtb + ((size_t)b * DVn + v) * Kn + k0 + h;
#pragma unroll
        for (int j4 = 0; j4 < 4; ++j4) {
            bf16x8 o;
#pragma unroll
            for (int j = 0; j < 8; ++j) {
                const int kk = h + j4 * 8 + j;
                o[j] = Ls[kk * 128 + (v ^ ((kk & 15) << 3))];
            }
            *(bf16x8*)(dst + j4 * 8) = o;
        }
    } else {
        // ---- sort path: counting sort of 2048 q-rows by valid_len, batch b ----
        const int b = blockIdx.x - 1536;
        __shared__ int hist[2048];
        __shared__ int part[256];
        int vq[8];
#pragma unroll
        for (int i = 0; i < 8; ++i) hist[i * 256 + tid] = 0;
        __syncthreads();
#pragma unroll
        for (int i = 0; i < 8; ++i) {
            vq[i] = VLg[b * Qn + i * 256 + tid];    // 1..2048
            atomicAdd(&hist[vq[i] - 1], 1);
        }
        __syncthreads();
        // exclusive scan over 2048 bins (8 per thread + block scan)
        int lex[8]; int s = 0;
#pragma unroll
        for (int j = 0; j < 8; ++j) { lex[j] = s; s += hist[tid * 8 + j]; }
        part[tid] = s;
        __syncthreads();
        for (int off = 1; off < 256; off <<= 1) {
            int v = (tid >= off) ? part[tid - off] : 0;
            __syncthreads();
            part[tid] += v;
            __syncthreads();
        }
        const int excl = part[tid] - s;
#pragma unroll
        for (int j = 0; j < 8; ++j) hist[tid * 8 + j] = excl + lex[j];
        __syncthreads();
        // scatter: ascending positions by valid_len
#pragma unroll
        for (int i = 0; i < 8; ++i) {
            const int pos = atomicAdd(&hist[vq[i] - 1], 1);
            perm[b * Qn + pos] = i * 256 + tid;
        }
    }
}

// epilogue helpers with LITERAL accumulator indices (no runtime Oacc[] index)
#define DUMP_ACC(ACC, DST)                                            \
    {                                                                 \
        _Pragma("unroll")                                             \
        for (int reg = 0; reg < 16; ++reg) {                          \
            const int row = (reg & 3) + 8 * (reg >> 2) + 4 * hi;      \
            (DST)[row * 32 + l31] = (ACC)[reg];                       \
        }                                                             \
    }
#define STORE_ACC(ACC, SRC, COLBASE)                                  \
    {                                                                 \
        _Pragma("unroll")                                             \
        for (int reg = 0; reg < 16; ++reg) {                          \
            const int row = (reg & 3) + 8 * (reg >> 2) + 4 * hi;      \
            const float o = (ACC)[reg] + (SRC)[row * 32 + l31];       \
            Og_b[(size_t)permSh[pair * 32 + row] * DVn + (COLBASE) + l31] \
                = o * invl[reg];                                      \
        }                                                             \
    }

// ---------- main attention kernel (R8 core + perm gather + early exit) ----------
__global__ __launch_bounds__(256, 2) void attn_kernel(
    const float* __restrict__ Qg, const short* __restrict__ Kb,
    const short* __restrict__ Vtb, const float* __restrict__ biasg,
    const int* __restrict__ VL, const int* __restrict__ perm,
    float* __restrict__ Og)
{
    // K tile: 64 rows x 256B, chunk XOR by (row&15)
    // V tile: 64 rows x 256B; row r holds v=2r (slots c<8) and v=2r+1 (c>=8),
    //         slot position p = c ^ (r&15)
    __shared__ __align__(16) short Ksh[2][64 * 128];   // 32768 B (epilogue: float slab)
    __shared__ __align__(16) short Vsh[2][64 * 128];   // 32768 B
    __shared__ __align__(16) float biasSh[2][64];      //   512 B
    __shared__ float Lsum[4][32];                      //   512 B
    __shared__ int   permSh[64];                       //   256 B -> 66816 B total

    const int tid  = threadIdx.x;
    const int lane = tid & 63;
    const int w    = tid >> 6;    // wave 0..3
    const int pair = w >> 1;      // q-strip: rows [pair*32, pair*32+32)
    const int half = w & 1;       // key-half (S and PV k-range), wave-uniform
    const int l31  = lane & 31;
    const int hi   = lane >> 5;

    const int lin  = blockIdx.x;          // 0..511 ; XCD = lin&7 (L2 locality)
    const int slot = lin >> 3;            // 0..63
    const int bsel = slot >> 5;           // batch parity within the XCD pair
    const int b    = (lin & 7) * 2 + bsel;
    // dual-robust zip ordering: f(s)+f(s^1)=33 and f(s)+f(s+32)=33
    const int t    = (slot & 31) >> 1;
    const int e    = slot & 1;
    const int q    = (e ^ bsel) ? (31 - t) : t;   // sorted job index 0..31
    const int lo   = q * BQ;

    const short* Kb_b = Kb  + (size_t)b * Kn * Dn;
    const short* Vt_b = Vtb + (size_t)b * DVn * Kn;
    const float* bias_b = biasg + b * Kn;
    float* Og_b = Og + (size_t)b * Qn * DVn;

    if (tid < 64) permSh[tid] = perm[b * Qn + lo + tid];
    __syncthreads();

    // ---- DMA source pointers ----
    const short* ksp[4]; int kdo[4];
    const short* vsp[4]; int vdo[4];
#pragma unroll
    for (int i = 0; i < 4; ++i) {
        const int rl = w * 16 + i * 4 + (lane >> 4);       // K tile row 0..63
        const int ch = (lane & 15) ^ (rl & 15);
        ksp[i] = Kb_b + (size_t)rl * Dn + ch * 8;
        kdo[i] = (w * 16 + i * 4) * 128;
        const int rv = w * 16 + i * 4 + (lane >> 4);       // V tile row 0..63
        const int cc = (lane & 15) ^ (rv & 15);            // source chunk
        const int vv = 2 * rv + (cc >> 3);
        vsp[i] = Vt_b + (size_t)vv * Kn + (cc & 7) * 8;
        vdo[i] = (w * 16 + i * 4) * 128;
    }

    // ---- Q fragments (gathered via perm): [n=l31][k=kt*16+hi*8+j] ----
    const int qperm = permSh[pair * 32 + l31];
    bf16x8 qf[8];
    {
        const float* qrow = Qg + ((size_t)b * Qn + qperm) * Dn;
#pragma unroll
        for (int kt = 0; kt < 8; ++kt) {
            const float* p = qrow + kt * 16 + hi * 8;
            float4 x0 = *(const float4*)(p);
            float4 x1 = *(const float4*)(p + 4);
            bf16x8 f;
            f[0]=f2bf(x0.x); f[1]=f2bf(x0.y); f[2]=f2bf(x0.z); f[3]=f2bf(x0.w);
            f[4]=f2bf(x1.x); f[5]=f2bf(x1.y); f[6]=f2bf(x1.z); f[7]=f2bf(x1.w);
            qf[kt] = f;
        }
    }
    const int vlq  = VL[b * Qn + qperm];
    // rows sorted ascending within the job -> max valid_len is the last row
    const int KEnd = ((VL[b * Qn + permSh[63]] + BK - 1) >> 6) << 6;

    f32x16 Oacc[4];   // v = nt*32 + l31, all 128 v; keys restricted to own half
#pragma unroll
    for (int nt = 0; nt < 4; ++nt)
#pragma unroll
        for (int j = 0; j < 16; ++j) Oacc[nt][j] = 0.f;
    float psum = 0.f;

    // prologue: DMA tile 0 into buffer 0
#pragma unroll
    for (int i = 0; i < 4; ++i) {
        gld16(ksp[i], &Ksh[0][kdo[i]]);
        gld16(vsp[i], &Vsh[0][vdo[i]]);
    }
    if (w == 0) gld4(bias_b + lane, &biasSh[0][0]);

    for (int k0k = 0; k0k < KEnd; k0k += BK) {
        const int buf = (k0k >> 6) & 1;
        __syncthreads();   // drains vmcnt(0): tile ready; prev readers done

        if (k0k + BK < KEnd) {
            const int nk = k0k + BK;
#pragma unroll
            for (int i = 0; i < 4; ++i) {
                gld16(ksp[i] + (size_t)nk * Dn, &Ksh[buf ^ 1][kdo[i]]);
                gld16(vsp[i] + nk,              &Vsh[buf ^ 1][vdo[i]]);
            }
            if (w == 0) gld4(bias_b + nk + lane, &biasSh[buf ^ 1][0]);
        }

        float4 bv[4];
#pragma unroll
        for (int rq = 0; rq < 4; ++rq)
            bv[rq] = *(const float4*)&biasSh[buf][half * 32 + rq * 8 + hi * 4];

        // ---- S^T = K_half . Q^T : one 32x32 tile per wave (8 MFMA) ----
        const short* kbuf = Ksh[buf];
        const int kr = half * 32 + l31;
        f32x16 Sv;
#pragma unroll
        for (int j = 0; j < 16; ++j) Sv[j] = 0.f;
#pragma unroll
        for (int kt = 0; kt < 8; ++kt) {
            bf16x8 kf = *(const bf16x8*)&kbuf[kr * 128 + (((kt*2 + hi) ^ (kr & 15)) * 8)];
            Sv = __builtin_amdgcn_mfma_f32_32x32x16_bf16(kf, qf[kt], Sv, 0, 0, 0);
        }

        // ---- softmax in exp2 domain (results back into Sv) ----
#pragma unroll
        for (int rq = 0; rq < 4; ++rq) {
#pragma unroll
            for (int r = 0; r < 4; ++r) {
                const int reg = rq * 4 + r;
                const int keyg = k0k + half * 32 + rq * 8 + hi * 4 + r;
                float a = fmaf(Sv[reg], SC2, bv[rq][r]);
                a = (keyg < vlq) ? a : -200.0f;
                const float p = exp2_raw(a);
                psum += p;
                Sv[reg] = p;
            }
        }

        // ---- PV: C-layout -> A-layout via lane^32 exchange; 8 MFMA ----
        const short* vbuf = Vsh[buf];
#pragma unroll
        for (int kt = 0; kt < 2; ++kt) {
            unsigned kAx = __builtin_amdgcn_perm(__float_as_uint(Sv[(2*kt)*4+1]),
                                                 __float_as_uint(Sv[(2*kt)*4+0]), 0x07060302u);
            unsigned kAy = __builtin_amdgcn_perm(__float_as_uint(Sv[(2*kt)*4+3]),
                                                 __float_as_uint(Sv[(2*kt)*4+2]), 0x07060302u);
            unsigned kBx = __builtin_amdgcn_perm(__float_as_uint(Sv[(2*kt+1)*4+1]),
                                                 __float_as_uint(Sv[(2*kt+1)*4+0]), 0x07060302u);
            unsigned kBy = __builtin_amdgcn_perm(__float_as_uint(Sv[(2*kt+1)*4+3]),
                                                 __float_as_uint(Sv[(2*kt+1)*4+2]), 0x07060302u);
            const unsigned sx = hi ? kAx : kBx;
            const unsigned sy = hi ? kAy : kBy;
            const unsigned rx = __shfl_xor(sx, 32);
            const unsigned ry = __shfl_xor(sy, 32);
            uint4 au;
            au.x = hi ? rx : kAx;
            au.y = hi ? ry : kAy;
            au.z = hi ? kBx : rx;
            au.w = hi ? kBy : ry;
            const bf16x8 af = __builtin_bit_cast(bf16x8, au);
            const int kc = half * 4 + kt * 2 + hi;   // key-chunk within 64-key tile
#pragma unroll
            for (int nt = 0; nt < 4; ++nt) {
                const int v  = nt * 32 + l31;
                const int r  = v >> 1;
                const int p  = ((v & 1) * 8 + kc) ^ (r & 15);
                bf16x8 vf = *(const bf16x8*)&vbuf[r * 128 + p * 8];
                Oacc[nt] = __builtin_amdgcn_mfma_f32_32x32x16_bf16(af, vf, Oacc[nt], 0, 0, 0);
            }
        }
    }

    // ---- epilogue: combine key-halves across wave pairs via LDS ----
    psum += __shfl_xor(psum, 32);
    if (lane < 32) Lsum[w][l31] = psum;
    __syncthreads();   // all waves done reading Ksh/Vsh -> safe to reuse Ksh

    float* slab = (float*)&Ksh[0][0];
    // write the half the PARTNER will store (literal Oacc indices; half is
    // wave-uniform so this is a scalar branch, not divergence)
    {
        float* dst0 = slab + ((pair * 2 + (1 - half)) * 2 + 0) * 1024;
        float* dst1 = slab + ((pair * 2 + (1 - half)) * 2 + 1) * 1024;
        if (half == 0) {
            DUMP_ACC(Oacc[2], dst0);
            DUMP_ACC(Oacc[3], dst1);
        } else {
            DUMP_ACC(Oacc[0], dst0);
            DUMP_ACC(Oacc[1], dst1);
        }
    }
    __syncthreads();

    float invl[16];
#pragma unroll
    for (int rq = 0; rq < 4; ++rq)
#pragma unroll
        for (int r = 0; r < 4; ++r) {
            const int ql = r + 8 * rq + 4 * hi;
            invl[rq*4+r] = 1.f / (Lsum[pair*2][ql] + Lsum[pair*2+1][ql]);
        }
    {
        const float* src0 = slab + ((pair * 2 + half) * 2 + 0) * 1024;
        const float* src1 = slab + ((pair * 2 + half) * 2 + 1) * 1024;
        if (half == 0) {
            STORE_ACC(Oacc[0], src0, 0);
            STORE_ACC(Oacc[1], src1, 32);
        } else {
            STORE_ACC(Oacc[2], src0, 64);
            STORE_ACC(Oacc[3], src1, 96);
        }
    }
}

extern "C" void kernel_launch(void* const* d_in, const int* in_sizes, int n_in,
                              void* d_out, int out_size, void* d_ws, size_t ws_size,
                              hipStream_t stream) {
    const float* Qg = (const float*)d_in[0];
    const float* Kg = (const float*)d_in[1];
    const float* Vg = (const float*)d_in[2];
    const int*   VL = (const int*)d_in[3];
    float* Og = (float*)d_out;
    (void)ws_size;

    // ws: Kb bf16 (8MB) | Vtb bf16 (8MB) | bias f32 (128KB) | perm int (128KB)
    char* ws = (char*)d_ws;
    short* Kb   = (short*)(ws);
    short* Vtb  = (short*)(ws + (size_t)Bn * Kn * Dn * 2);
    float* bias = (float*)(ws + (size_t)Bn * Kn * Dn * 4);
    int*   perm = (int*)  (ws + (size_t)Bn * Kn * Dn * 4 + 131072);

    prep_kv<<<dim3(1552), dim3(256), 0, stream>>>(Kg, Vg, VL, Kb, Vtb, bias, perm);
    attn_kernel<<<dim3(512), dim3(256), 0, stream>>>(Qg, Kb, Vtb, bias, VL, perm, Og);
}